// Round 1
// baseline (81880.438 us; speedup 1.0000x reference)
//
#include <hip/hip_runtime.h>
#include <math.h>

#define NCH 2048
#define NT 256

// Static device scratch (avoids any assumption about ws_size).
// X spectrum, row-pass intermediate, per-res ring outputs, owner map.
__device__ float2 g_X[(size_t)NCH * 128 * 65];     // 136 MB
__device__ float2 g_Y[(size_t)NCH * 128 * 65];     // 136 MB
__device__ float2 g_ring[(size_t)NCH * 57 * 132];  // 123 MB
__device__ int    g_owner[64 * 33];

__device__ __forceinline__ float gelu_exact(float v) {
  return 0.5f * v * (1.0f + erff(v * 0.70710678118654752440f));
}

// ---------------------------------------------------------------------------
// R1: row-wise DFT along v: Y[ch,u,k2] = sum_v x[ch,u,v] e^{-2pi i k2 v/128}
// ---------------------------------------------------------------------------
__global__ __launch_bounds__(NT) void r1_kernel(const float* __restrict__ x) {
  __shared__ float xb[16 * 128];
  __shared__ float tw[256];
  int ch = blockIdx.x >> 3, grp = blockIdx.x & 7;
  int tid = threadIdx.x;
  for (int t = tid; t < 128; t += NT) {
    float s, co; sincosf(6.283185307179586f * (float)t / 128.0f, &s, &co);
    tw[2 * t] = co; tw[2 * t + 1] = s;
  }
  const float* xp = x + ((size_t)ch * 128 + grp * 16) * 128;
  for (int i = tid; i < 16 * 128; i += NT) xb[i] = xp[i];
  __syncthreads();
  for (int idx = tid; idx < 16 * 65; idx += NT) {
    int u = idx / 65, k2 = idx - 65 * u;
    const float* row = xb + u * 128;
    float ar = 0.f, ai = 0.f;
    int t = 0;
    for (int v = 0; v < 128; v++) {
      float xv = row[v];
      ar += xv * tw[2 * t]; ai -= xv * tw[2 * t + 1];
      t += k2; if (t >= 128) t -= 128;
    }
    g_Y[((size_t)ch * 128 + grp * 16 + u) * 65 + k2] = make_float2(ar, ai);
  }
}

// ---------------------------------------------------------------------------
// R2: col-wise DFT along u + 1/16384 norm: X[ch,k1,k2]
// Pairs k1 and k1+64 via (-1)^u sign trick.
// ---------------------------------------------------------------------------
__global__ __launch_bounds__(NT) void r2_kernel() {
  __shared__ float2 yb[128 * 8];
  __shared__ float tw[256];
  int ch = blockIdx.x / 9, cg = blockIdx.x - 9 * ch;
  int c0 = cg * 8, nc = min(8, 65 - c0);
  int tid = threadIdx.x;
  for (int t = tid; t < 128; t += NT) {
    float s, co; sincosf(6.283185307179586f * (float)t / 128.0f, &s, &co);
    tw[2 * t] = co; tw[2 * t + 1] = s;
  }
  for (int i = tid; i < 128 * nc; i += NT) {
    int u = i / nc, j = i - nc * u;
    yb[u * 8 + j] = g_Y[((size_t)ch * 128 + u) * 65 + c0 + j];
  }
  __syncthreads();
  const float inv = 1.0f / 16384.0f;
  for (int idx = tid; idx < 64 * nc; idx += NT) {
    int k1 = idx & 63, j = idx >> 6;
    float ar = 0.f, ai = 0.f, br = 0.f, bi = 0.f;
    int t = 0;
    for (int u = 0; u < 128; u += 2) {
      float2 e = yb[u * 8 + j];
      float co = tw[2 * t], si = tw[2 * t + 1];
      float pr = e.x * co + e.y * si, pi = e.y * co - e.x * si;
      ar += pr; ai += pi; br += pr; bi += pi;
      t += k1; if (t >= 128) t -= 128;
      e = yb[(u + 1) * 8 + j];
      co = tw[2 * t]; si = tw[2 * t + 1];
      pr = e.x * co + e.y * si; pi = e.y * co - e.x * si;
      ar += pr; ai += pi; br -= pr; bi -= pi;
      t += k1; if (t >= 128) t -= 128;
    }
    g_X[((size_t)ch * 128 + k1) * 65 + c0 + j]      = make_float2(ar * inv, ai * inv);
    g_X[((size_t)ch * 128 + k1 + 64) * 65 + c0 + j] = make_float2(br * inv, bi * inv);
  }
}

// ---------------------------------------------------------------------------
// Owner map: which (res, ring-slot) last writes each x_out[rr,k2] cell,
// replicating the reference's sequential overwrite order.
// Ring slot layout per res>16: [0..h]=F[h][k2], [h+1..2h+1]=F[c-h][k2],
// [2h+2 .. 2h+1+c]=F[i][h]. res==16: full 8x5 block, slot=k1*5+k2.
// ---------------------------------------------------------------------------
__device__ __forceinline__ int owner_slot(int rr, int k2, int ri) {
  if (ri == 0) {  // base res=16 square
    if (k2 <= 4) {
      if (rr <= 3) return rr * 5 + k2;
      if (rr >= 60) return (rr - 56) * 5 + k2;
    }
    return -1;
  }
  int res = 16 + 2 * ri, c = res / 2, h = c / 2;
  if (c & 1) {
    if (rr == h && k2 <= h) return k2;
    if (rr == 64 - h && k2 <= h) return (h + 1) + k2;
    if (k2 == h) {
      if (rr <= h) return 2 * (h + 1) + rr;
      if (rr >= 64 - h) return 2 * (h + 1) + (rr - 64 + c);
    }
  } else {
    if (rr == 64 - h && k2 <= h) return (h + 1) + k2;
    if (k2 == h) {
      if (rr >= 64 - h) return 2 * (h + 1) + (rr - 64 + c);
      if (rr < h) return 2 * (h + 1) + rr;
    }
  }
  return -1;
}

__global__ __launch_bounds__(NT) void owner_kernel() {
  int cell = blockIdx.x * NT + threadIdx.x;
  if (cell >= 64 * 33) return;
  int rr = cell / 33, k2 = cell - 33 * (cell / 33);
  int result = -1;
  for (int ri = 56; ri >= 0 && result < 0; ri--) {
    int slot = owner_slot(rr, k2, ri);
    if (slot >= 0) result = ri * 256 + slot;
  }
  g_owner[cell] = result;
}

// ---------------------------------------------------------------------------
// Per-(channel,res) pipeline, fully LDS-resident.
// ---------------------------------------------------------------------------
__global__ __launch_bounds__(NT) void pipe_kernel(const float* __restrict__ x, int res_hi) {
  int rorder = blockIdx.x / NCH;
  int ch = blockIdx.x - rorder * NCH;
  int r = res_hi - 2 * rorder;
  const int tid = threadIdx.x;
  int c = r >> 1, cp1 = c + 1, m = c, c2 = (c >> 1) + 1, h = c >> 1;
  int rp2 = (m + 1) >> 1, rn2 = m >> 1;
  bool is128 = (r == 128);

  extern __shared__ float lds[];
  float* tw = lds;
  int o = 2 * r;
  float2* ET = (float2*)(lds + o); if (!is128) o += 2 * r * cp1;  // E' then T in place
  float2* Gd = (float2*)(lds + o); o += 2 * m * c2;               // band spectrum G
  float2* CB = (float2*)(lds + o); if (!is128) o += 8 * r;        // A1 column buffer
  float*  SB = lds + o; o += 8 * r;                               // 8 spatial rows
  float2* TB = (float2*)(lds + o); o += 16 * c2;                  // small row-spectra
  float* P;
  if (is128) { P = lds + o; } else { P = (float*)ET; }            // pooled c x c (+P1), overlays ET
  float2* P1 = (float2*)(P + c * c);

  for (int t = tid; t < r; t += NT) {
    float s, co; sincosf(6.283185307179586f * (float)t / (float)r, &s, &co);
    tw[2 * t] = co; tw[2 * t + 1] = s;
  }
  __syncthreads();

  const float2* Xc = g_X + (size_t)ch * (128 * 65);

  if (!is128) {
    // ---- load crop E' with numpy-exact symmetrization of cols 0 and c ----
    for (int idx = tid; idx < r * cp1; idx += NT) {
      int row = idx / cp1, k2 = idx - row * cp1;
      int src = (row < c) ? row : (128 - r + row);
      float2 v = Xc[src * 65 + k2];
      if (k2 == 0 || k2 == c) {
        int prow = (r - row) % r;
        int psrc = (prow < c) ? prow : (128 - r + prow);
        float2 pv = Xc[psrc * 65 + k2];
        v.x = 0.5f * (v.x + pv.x);
        v.y = 0.5f * (v.y - pv.y);
      }
      ET[idx] = v;
    }
    __syncthreads();
    // ---- A1: in-place column DFT (k1 -> u), u paired with u+c ----
    for (int b0 = 0; b0 < cp1; b0 += 4) {
      int nb = min(4, cp1 - b0);
      for (int idx = tid; idx < r * nb; idx += NT) {
        int row = idx % r, j = idx / r;
        CB[j * r + row] = ET[row * cp1 + b0 + j];
      }
      __syncthreads();
      for (int idx = tid; idx < c * nb; idx += NT) {
        int u = idx % c, j = idx / c;
        const float2* col = CB + j * r;
        float ar = 0.f, ai = 0.f, br = 0.f, bi = 0.f;
        int t = 0;
        for (int row = 0; row < r; row += 2) {
          float2 e = col[row];
          float co = tw[2 * t], si = tw[2 * t + 1];
          float pr = e.x * co - e.y * si, pi = e.x * si + e.y * co;
          ar += pr; ai += pi; br += pr; bi += pi;
          t += u; if (t >= r) t -= r;
          e = col[row + 1];
          co = tw[2 * t]; si = tw[2 * t + 1];
          pr = e.x * co - e.y * si; pi = e.x * si + e.y * co;
          ar += pr; ai += pi; br -= pr; bi -= pi;
          t += u; if (t >= r) t -= r;
        }
        ET[u * cp1 + b0 + j]       = make_float2(ar, ai);
        ET[(u + c) * cp1 + b0 + j] = make_float2(br, bi);
      }
      __syncthreads();
    }
  }

  // ---- A2: streamed u-blocks: synthesis (v), GELU, row analysis, G accum ----
  for (int ub = 0; ub < r; ub += 8) {
    int nu = min(8, r - ub);
    if (!is128) {
      for (int idx = tid; idx < nu * c; idx += NT) {
        int v = idx % c, i = idx / c;
        const float2* Tr = ET + (ub + i) * cp1;
        float s0 = Tr[0].x, sc = Tr[c].x;
        float ea = 0.f, eb = 0.f;
        int t = v;
        for (int k2 = 1; k2 < c; k2++) {
          float2 e = Tr[k2];
          float term = e.x * tw[2 * t] - e.y * tw[2 * t + 1];
          ea += term;
          eb += (k2 & 1) ? -term : term;
          t += v; if (t >= r) t -= r;
        }
        float sva = (v & 1) ? -sc : sc;
        float svb = ((v + c) & 1) ? -sc : sc;
        SB[i * r + v]     = gelu_exact(s0 + sva + 2.f * ea);
        SB[i * r + v + c] = gelu_exact(s0 + svb + 2.f * eb);
      }
    } else {
      const float* xc = x + (size_t)ch * 128 * 128;
      for (int idx = tid; idx < nu * r; idx += NT) {
        int v = idx % r, i = idx / r;
        SB[i * r + v] = gelu_exact(xc[(ub + i) * 128 + v]);
      }
    }
    __syncthreads();
    // row analysis: G1 block
    for (int idx = tid; idx < nu * c2; idx += NT) {
      int k2 = idx % c2, i = idx / c2;
      const float* g = SB + i * r;
      float ar = 0.f, ai = 0.f;
      int t = 0;
      for (int v = 0; v < r; v++) {
        float gv = g[v];
        ar += gv * tw[2 * t]; ai -= gv * tw[2 * t + 1];
        t += k2; if (t >= r) t -= r;
      }
      TB[idx] = make_float2(ar, ai);
    }
    __syncthreads();
    // accumulate band spectrum G (rows f_j)
    for (int idx = tid; idx < m * c2; idx += NT) {
      int j = idx / c2, k2 = idx - j * c2;
      int f = (j < rp2) ? j : (r - rn2 + (j - rp2));
      float gr, gi;
      if (ub == 0) { gr = 0.f; gi = 0.f; }
      else { float2 gp = Gd[idx]; gr = gp.x; gi = gp.y; }
      int t = (f * ub) % r;
      for (int i = 0; i < nu; i++) {
        float2 e = TB[i * c2 + k2];
        float co = tw[2 * t], si = tw[2 * t + 1];
        gr += e.x * co + e.y * si;
        gi += e.y * co - e.x * si;
        t += f; if (t >= r) t -= r;
      }
      Gd[idx] = make_float2(gr, gi);
    }
    __syncthreads();
  }
  {
    float invr2 = 1.0f / ((float)r * (float)r);
    for (int idx = tid; idx < m * c2; idx += NT) { Gd[idx].x *= invr2; Gd[idx].y *= invr2; }
  }
  __syncthreads();

  // ---- C: streamed smoothing synthesis + 2x2 maxpool into P ----
  for (int ub = 0; ub < r; ub += 8) {
    int nu = min(8, r - ub);
    for (int idx = tid; idx < nu * c2; idx += NT) {
      int k2 = idx % c2, i = idx / c2;
      int u = ub + i;
      float trr = 0.f, tii = 0.f;
      int t = 0;
      for (int j = 0; j < rp2; j++) {
        float2 e = Gd[j * c2 + k2];
        float co = tw[2 * t], si = tw[2 * t + 1];
        trr += e.x * co - e.y * si; tii += e.x * si + e.y * co;
        t += u; if (t >= r) t -= r;
      }
      t = (int)(((long)(r - rn2) * u) % r);
      for (int j = rp2; j < m; j++) {
        float2 e = Gd[j * c2 + k2];
        float co = tw[2 * t], si = tw[2 * t + 1];
        trr += e.x * co - e.y * si; tii += e.x * si + e.y * co;
        t += u; if (t >= r) t -= r;
      }
      TB[idx] = make_float2(trr, tii);
    }
    __syncthreads();
    for (int idx = tid; idx < nu * c; idx += NT) {
      int v = idx % c, i = idx / c;
      const float2* T2 = TB + i * c2;
      float base = T2[0].x;
      float ea = 0.f, eb = 0.f;
      int t = v;
      for (int k2 = 1; k2 < c2; k2++) {
        float2 e = T2[k2];
        float term = e.x * tw[2 * t] - e.y * tw[2 * t + 1];
        ea += term;
        eb += (k2 & 1) ? -term : term;
        t += v; if (t >= r) t -= r;
      }
      SB[i * r + v]     = base + 2.f * ea;
      SB[i * r + v + c] = base + 2.f * eb;
    }
    __syncthreads();
    for (int idx = tid; idx < (nu >> 1) * c; idx += NT) {
      int jj = idx % c, i2 = idx / c;
      const float* s0 = SB + (2 * i2) * r;
      const float* s1 = SB + (2 * i2 + 1) * r;
      float pv = fmaxf(fmaxf(s0[2 * jj], s0[2 * jj + 1]), fmaxf(s1[2 * jj], s1[2 * jj + 1]));
      P[(ub / 2 + i2) * c + jj] = pv;
    }
    __syncthreads();
  }

  // ---- E: ring DFT of pooled image ----
  int hp1 = h + 1;
  for (int idx = tid; idx < c * hp1; idx += NT) {
    int k2 = idx % hp1, i = idx / hp1;
    const float* prow = P + i * c;
    float ar = 0.f, ai = 0.f;
    int t = 0, dt = (2 * k2) % r;
    for (int jj = 0; jj < c; jj++) {
      float pv = prow[jj];
      ar += pv * tw[2 * t]; ai -= pv * tw[2 * t + 1];
      t += dt; if (t >= r) t -= r;
    }
    P1[idx] = make_float2(ar, ai);
  }
  __syncthreads();
  float invcc = 1.0f / ((float)c * (float)c);
  float2* ringp = g_ring + ((size_t)ch * 57 + (size_t)((r - 16) >> 1)) * 132;
  if (r == 16) {
    for (int idx = tid; idx < 40; idx += NT) {
      int k2 = idx % 5, k1 = idx / 5;
      float ar = 0.f, ai = 0.f; int t = 0, dt = (2 * k1) % r;
      for (int i = 0; i < c; i++) {
        float2 e = P1[i * hp1 + k2];
        float co = tw[2 * t], si = tw[2 * t + 1];
        ar += e.x * co + e.y * si; ai += e.y * co - e.x * si;
        t += dt; if (t >= r) t -= r;
      }
      ringp[idx] = make_float2(ar * invcc, ai * invcc);
    }
  } else {
    int nA = hp1, total = 2 * nA + c;
    for (int idx = tid; idx < total; idx += NT) {
      int k1, k2;
      if (idx < nA) { k1 = h; k2 = idx; }
      else if (idx < 2 * nA) { k1 = c - h; k2 = idx - nA; }
      else { k1 = idx - 2 * nA; k2 = h; }
      float ar = 0.f, ai = 0.f; int t = 0, dt = (2 * k1) % r;
      for (int i = 0; i < c; i++) {
        float2 e = P1[i * hp1 + k2];
        float co = tw[2 * t], si = tw[2 * t + 1];
        ar += e.x * co + e.y * si; ai += e.y * co - e.x * si;
        t += dt; if (t >= r) t -= r;
      }
      ringp[idx] = make_float2(ar * invcc, ai * invcc);
    }
  }
}

// ---------------------------------------------------------------------------
// Final assembly: out = Hermitian-extension projection of x_out (no FFTs).
// ---------------------------------------------------------------------------
__device__ __forceinline__ float2 loadA(int ch, int k1, int k2) {
  int o = g_owner[k1 * 33 + k2];
  if (o < 0) return make_float2(0.f, 0.f);
  return g_ring[((size_t)ch * 57 + (o >> 8)) * 132 + (o & 255)];
}

__global__ __launch_bounds__(NT) void assemble_kernel(float* __restrict__ out) {
  size_t gid = (size_t)blockIdx.x * NT + threadIdx.x;
  if (gid >= (size_t)NCH * 4096) return;
  int ch = (int)(gid >> 12);
  int rem = (int)(gid & 4095);
  int k1 = rem >> 6, k2f = rem & 63;
  float2 v;
  if (k2f <= 32) {
    float2 a = loadA(ch, k1, k2f);
    if (k2f == 0 || k2f == 32) {
      float2 b = loadA(ch, (64 - k1) & 63, k2f);
      v = make_float2(0.5f * (a.x + b.x), 0.5f * (a.y - b.y));
    } else v = a;
  } else {
    float2 a = loadA(ch, (64 - k1) & 63, 64 - k2f);
    v = make_float2(a.x, -a.y);
  }
  out[2 * gid] = v.x;
  out[2 * gid + 1] = v.y;
}

// ---------------------------------------------------------------------------
static int lds_floats(int r) {
  int c = r / 2, cp1 = c + 1, m = c, c2 = c / 2 + 1;
  bool is128 = (r == 128);
  int o = 2 * r;
  if (!is128) o += 2 * r * cp1;
  o += 2 * m * c2;
  if (!is128) o += 8 * r;
  o += 8 * r;
  o += 16 * c2;
  if (is128) o += c * (r + 2);
  return o;
}

extern "C" void kernel_launch(void* const* d_in, const int* in_sizes, int n_in,
                              void* d_out, int out_size, void* d_ws, size_t ws_size,
                              hipStream_t stream) {
  (void)in_sizes; (void)n_in; (void)d_ws; (void)ws_size; (void)out_size;
  const float* x = (const float*)d_in[0];
  float* out = (float*)d_out;

  // Allow >64KB dynamic LDS for the large-res bucket (gfx950: 160 KiB/CU).
  hipFuncSetAttribute((const void*)pipe_kernel,
                      hipFuncAttributeMaxDynamicSharedMemorySize, 160 * 1024);

  hipLaunchKernelGGL(owner_kernel, dim3(9), dim3(NT), 0, stream);
  hipLaunchKernelGGL(r1_kernel, dim3(NCH * 8), dim3(NT), 0, stream, x);
  hipLaunchKernelGGL(r2_kernel, dim3(NCH * 9), dim3(NT), 0, stream);

  // Buckets by LDS footprint; biggest work first within each launch.
  hipLaunchKernelGGL(pipe_kernel, dim3(15 * NCH), dim3(NT), (size_t)lds_floats(126) * 4, stream, x, 126); // 98..126
  hipLaunchKernelGGL(pipe_kernel, dim3(1 * NCH),  dim3(NT), (size_t)lds_floats(128) * 4, stream, x, 128); // 128 (identity stage A)
  hipLaunchKernelGGL(pipe_kernel, dim3(16 * NCH), dim3(NT), (size_t)lds_floats(96) * 4,  stream, x, 96);  // 66..96
  hipLaunchKernelGGL(pipe_kernel, dim3(16 * NCH), dim3(NT), (size_t)lds_floats(64) * 4,  stream, x, 64);  // 34..64
  hipLaunchKernelGGL(pipe_kernel, dim3(9 * NCH),  dim3(NT), (size_t)lds_floats(32) * 4,  stream, x, 32);  // 16..32

  hipLaunchKernelGGL(assemble_kernel, dim3((NCH * 4096) / NT), dim3(NT), 0, stream, out);
}

// Round 2
// 38223.404 us; speedup vs baseline: 2.1422x; 2.1422x over previous
//
#include <hip/hip_runtime.h>
#include <math.h>

#define NCH 2048
#define NT 256

// Static device scratch (avoids any assumption about ws_size).
__device__ float2 g_X[(size_t)NCH * 128 * 65];     // 136 MB
__device__ float2 g_Y[(size_t)NCH * 128 * 65];     // 136 MB
__device__ float2 g_ring[(size_t)NCH * 57 * 132];  // 123 MB
__device__ int    g_owner[64 * 33];

__device__ __forceinline__ float gelu_exact(float v) {
  return 0.5f * v * (1.0f + erff(v * 0.70710678118654752440f));
}

// incremental complex rotation: (co,si) *= (cs,ss)
#define ROT(co, si, cs, ss) { float _n = co * cs - si * ss; si = si * cs + co * ss; co = _n; }

// ---------------------------------------------------------------------------
// R1: row-wise DFT along v: Y[ch,u,k2] = sum_v x[ch,u,v] e^{-2pi i k2 v/128}
// ---------------------------------------------------------------------------
__global__ __launch_bounds__(NT) void r1_kernel(const float* __restrict__ x) {
  __shared__ float xb[16 * 128];
  __shared__ float tw[256];
  int ch = blockIdx.x >> 3, grp = blockIdx.x & 7;
  int tid = threadIdx.x;
  for (int t = tid; t < 128; t += NT) {
    float s, co; sincosf(6.283185307179586f * (float)t / 128.0f, &s, &co);
    tw[2 * t] = co; tw[2 * t + 1] = s;
  }
  const float* xp = x + ((size_t)ch * 128 + grp * 16) * 128;
  for (int i = tid; i < 16 * 128; i += NT) xb[i] = xp[i];
  __syncthreads();
  for (int idx = tid; idx < 16 * 65; idx += NT) {
    int u = idx / 65, k2 = idx - 65 * u;
    const float* row = xb + u * 128;
    float ck = tw[2 * k2], sk = tw[2 * k2 + 1];
    float co = 1.f, si = 0.f;
    float ar = 0.f, ai = 0.f;
    for (int v = 0; v < 128; v += 2) {
      float xv = row[v];
      ar += xv * co; ai -= xv * si;
      ROT(co, si, ck, sk);
      xv = row[v + 1];
      ar += xv * co; ai -= xv * si;
      ROT(co, si, ck, sk);
    }
    g_Y[((size_t)ch * 128 + grp * 16 + u) * 65 + k2] = make_float2(ar, ai);
  }
}

// ---------------------------------------------------------------------------
// R2: col-wise DFT along u + 1/16384 norm. Pairs k1 and k1+64 via (-1)^u.
// ---------------------------------------------------------------------------
__global__ __launch_bounds__(NT) void r2_kernel() {
  __shared__ float2 yb[128 * 8];
  __shared__ float tw[256];
  int ch = blockIdx.x / 9, cg = blockIdx.x - 9 * ch;
  int c0 = cg * 8, nc = min(8, 65 - c0);
  int tid = threadIdx.x;
  for (int t = tid; t < 128; t += NT) {
    float s, co; sincosf(6.283185307179586f * (float)t / 128.0f, &s, &co);
    tw[2 * t] = co; tw[2 * t + 1] = s;
  }
  for (int i = tid; i < 128 * nc; i += NT) {
    int u = i / nc, j = i - nc * u;
    yb[u * 8 + j] = g_Y[((size_t)ch * 128 + u) * 65 + c0 + j];
  }
  __syncthreads();
  const float inv = 1.0f / 16384.0f;
  for (int idx = tid; idx < 64 * nc; idx += NT) {
    int k1 = idx & 63, j = idx >> 6;
    float ck = tw[2 * k1], sk = tw[2 * k1 + 1];
    float co = 1.f, si = 0.f;
    float ar = 0.f, ai = 0.f, br = 0.f, bi = 0.f;
    for (int u = 0; u < 128; u += 2) {
      float2 e = yb[u * 8 + j];
      float pr = e.x * co + e.y * si, pi = e.y * co - e.x * si;
      ar += pr; ai += pi; br += pr; bi += pi;
      ROT(co, si, ck, sk);
      e = yb[(u + 1) * 8 + j];
      pr = e.x * co + e.y * si; pi = e.y * co - e.x * si;
      ar += pr; ai += pi; br -= pr; bi -= pi;
      ROT(co, si, ck, sk);
    }
    g_X[((size_t)ch * 128 + k1) * 65 + c0 + j]      = make_float2(ar * inv, ai * inv);
    g_X[((size_t)ch * 128 + k1 + 64) * 65 + c0 + j] = make_float2(br * inv, bi * inv);
  }
}

// ---------------------------------------------------------------------------
// Owner map (reference's sequential overwrite order).
// ---------------------------------------------------------------------------
__device__ __forceinline__ int owner_slot(int rr, int k2, int ri) {
  if (ri == 0) {
    if (k2 <= 4) {
      if (rr <= 3) return rr * 5 + k2;
      if (rr >= 60) return (rr - 56) * 5 + k2;
    }
    return -1;
  }
  int res = 16 + 2 * ri, c = res / 2, h = c / 2;
  if (c & 1) {
    if (rr == h && k2 <= h) return k2;
    if (rr == 64 - h && k2 <= h) return (h + 1) + k2;
    if (k2 == h) {
      if (rr <= h) return 2 * (h + 1) + rr;
      if (rr >= 64 - h) return 2 * (h + 1) + (rr - 64 + c);
    }
  } else {
    if (rr == 64 - h && k2 <= h) return (h + 1) + k2;
    if (k2 == h) {
      if (rr >= 64 - h) return 2 * (h + 1) + (rr - 64 + c);
      if (rr < h) return 2 * (h + 1) + rr;
    }
  }
  return -1;
}

__global__ __launch_bounds__(NT) void owner_kernel() {
  int cell = blockIdx.x * NT + threadIdx.x;
  if (cell >= 64 * 33) return;
  int rr = cell / 33, k2 = cell - 33 * (cell / 33);
  int result = -1;
  for (int ri = 56; ri >= 0 && result < 0; ri--) {
    int slot = owner_slot(rr, k2, ri);
    if (slot >= 0) result = ri * 256 + slot;
  }
  g_owner[cell] = result;
}

// ---------------------------------------------------------------------------
// Per-(channel,res) pipeline, fully LDS-resident. NTT = block size.
// ---------------------------------------------------------------------------
template <int NTT>
__global__ __launch_bounds__(NTT) void pipe_kernel(const float* __restrict__ x, int res_hi) {
  const int nb = (NTT == 512) ? 8 : 4;
  const int nu = (NTT == 512) ? 16 : 8;
  int rorder = blockIdx.x / NCH;
  int ch = blockIdx.x - rorder * NCH;
  int r = res_hi - 2 * rorder;
  const int tid = threadIdx.x;
  int c = r >> 1, cp1 = c + 1, m = c, c2 = (c >> 1) + 1, h = c >> 1;
  int sp = (cp1 & 1) ? cp1 : cp1 + 1;   // padded (odd) row stride for ET
  int rp2 = (m + 1) >> 1, rn2 = m >> 1;
  bool is128 = (r == 128);

  extern __shared__ float lds[];
  float* tw = lds;
  int o = 2 * r;
  float2* ET = (float2*)(lds + o); if (!is128) o += 2 * r * sp;
  float2* Gd = (float2*)(lds + o); o += 2 * m * c2;
  float2* CB = (float2*)(lds + o); if (!is128) o += 2 * nb * r;
  float*  SB = lds + o; o += nu * r;
  float2* TB = (float2*)(lds + o); o += 2 * nu * c2;
  float* P;
  if (is128) { P = lds + o; } else { P = (float*)ET; }
  float2* P1 = (float2*)(P + c * c);

  for (int t = tid; t < r; t += NTT) {
    float s, co; sincosf(6.283185307179586f * (float)t / (float)r, &s, &co);
    tw[2 * t] = co; tw[2 * t + 1] = s;
  }
  __syncthreads();

  const float2* Xc = g_X + (size_t)ch * (128 * 65);

  if (!is128) {
    // ---- load crop E' with numpy-exact symmetrization of cols 0 and c ----
    for (int idx = tid; idx < r * cp1; idx += NTT) {
      int row = idx / cp1, k2 = idx - row * cp1;
      int src = (row < c) ? row : (128 - r + row);
      float2 v = Xc[src * 65 + k2];
      if (k2 == 0 || k2 == c) {
        int prow = (r - row) % r;
        int psrc = (prow < c) ? prow : (128 - r + prow);
        float2 pv = Xc[psrc * 65 + k2];
        v.x = 0.5f * (v.x + pv.x);
        v.y = 0.5f * (v.y - pv.y);
      }
      ET[row * sp + k2] = v;
    }
    __syncthreads();
    // ---- A1: in-place column DFT (k1 -> u), u paired with u+c ----
    for (int b0 = 0; b0 < cp1; b0 += nb) {
      int nbc = min(nb, cp1 - b0);
      for (int idx = tid; idx < r * nbc; idx += NTT) {
        int row = idx % r, j = idx / r;
        CB[j * r + row] = ET[row * sp + b0 + j];
      }
      __syncthreads();
      for (int idx = tid; idx < c * nbc; idx += NTT) {
        int u = idx % c, j = idx / c;
        const float2* col = CB + j * r;
        float cu = tw[2 * u], su = tw[2 * u + 1];
        float co = 1.f, si = 0.f;
        float ar = 0.f, ai = 0.f, br = 0.f, bi = 0.f;
        for (int row = 0; row < r; row += 2) {
          float2 e = col[row];
          float pr = e.x * co - e.y * si, pi = e.x * si + e.y * co;
          ar += pr; ai += pi; br += pr; bi += pi;
          ROT(co, si, cu, su);
          e = col[row + 1];
          pr = e.x * co - e.y * si; pi = e.x * si + e.y * co;
          ar += pr; ai += pi; br -= pr; bi -= pi;
          ROT(co, si, cu, su);
        }
        ET[u * sp + b0 + j]       = make_float2(ar, ai);
        ET[(u + c) * sp + b0 + j] = make_float2(br, bi);
      }
      __syncthreads();
    }
  }

  // ---- A2: streamed u-blocks: synthesis (v), GELU, row analysis, G accum ----
  for (int ub = 0; ub < r; ub += nu) {
    int nuc = min(nu, r - ub);
    if (!is128) {
      for (int idx = tid; idx < nuc * c; idx += NTT) {
        int v = idx % c, i = idx / c;
        const float2* Tr = ET + (ub + i) * sp;
        float s0 = Tr[0].x, scN = Tr[c].x;
        float cv = tw[2 * v], sv = tw[2 * v + 1];
        float co = cv, si = sv;
        float ea = 0.f, eb = 0.f;
        int k2 = 1;
        for (; k2 + 1 < c; k2 += 2) {
          float2 e = Tr[k2];
          float term = e.x * co - e.y * si;
          ea += term; eb -= term;
          ROT(co, si, cv, sv);
          e = Tr[k2 + 1];
          term = e.x * co - e.y * si;
          ea += term; eb += term;
          ROT(co, si, cv, sv);
        }
        if (k2 < c) {  // k2 = c-1 (odd)
          float2 e = Tr[k2];
          float term = e.x * co - e.y * si;
          ea += term; eb -= term;
        }
        float sva = (v & 1) ? -scN : scN;
        float svb = ((v + c) & 1) ? -scN : scN;
        SB[i * r + v]     = gelu_exact(s0 + sva + 2.f * ea);
        SB[i * r + v + c] = gelu_exact(s0 + svb + 2.f * eb);
      }
    } else {
      const float* xc = x + (size_t)ch * 128 * 128;
      for (int idx = tid; idx < nuc * r; idx += NTT) {
        int v = idx % r, i = idx / r;
        SB[i * r + v] = gelu_exact(xc[(ub + i) * 128 + v]);
      }
    }
    __syncthreads();
    // row analysis
    for (int idx = tid; idx < nuc * c2; idx += NTT) {
      int k2 = idx % c2, i = idx / c2;
      const float* g = SB + i * r;
      float ck = tw[2 * k2], sk = tw[2 * k2 + 1];
      float co = 1.f, si = 0.f;
      float ar = 0.f, ai = 0.f;
      for (int v = 0; v < r; v += 2) {
        float gv = g[v];
        ar += gv * co; ai -= gv * si;
        ROT(co, si, ck, sk);
        gv = g[v + 1];
        ar += gv * co; ai -= gv * si;
        ROT(co, si, ck, sk);
      }
      TB[idx] = make_float2(ar, ai);
    }
    __syncthreads();
    // accumulate band spectrum G (broadcast-friendly: keep LDS twiddles)
    for (int idx = tid; idx < m * c2; idx += NTT) {
      int j = idx / c2, k2 = idx - j * c2;
      int f = (j < rp2) ? j : (r - rn2 + (j - rp2));
      float gr, gi;
      if (ub == 0) { gr = 0.f; gi = 0.f; }
      else { float2 gp = Gd[idx]; gr = gp.x; gi = gp.y; }
      int t = (f * ub) % r;
      for (int i = 0; i < nuc; i++) {
        float2 e = TB[i * c2 + k2];
        float co = tw[2 * t], si = tw[2 * t + 1];
        gr += e.x * co + e.y * si;
        gi += e.y * co - e.x * si;
        t += f; if (t >= r) t -= r;
      }
      Gd[idx] = make_float2(gr, gi);
    }
    __syncthreads();
  }
  {
    float invr2 = 1.0f / ((float)r * (float)r);
    for (int idx = tid; idx < m * c2; idx += NTT) { Gd[idx].x *= invr2; Gd[idx].y *= invr2; }
  }
  __syncthreads();

  // ---- C: streamed smoothing synthesis + 2x2 maxpool into P ----
  for (int ub = 0; ub < r; ub += nu) {
    int nuc = min(nu, r - ub);
    for (int idx = tid; idx < nuc * c2; idx += NTT) {
      int k2 = idx % c2, i = idx / c2;
      int u = ub + i;
      float trr = 0.f, tii = 0.f;
      int t = 0;
      for (int j = 0; j < rp2; j++) {
        float2 e = Gd[j * c2 + k2];
        float co = tw[2 * t], si = tw[2 * t + 1];
        trr += e.x * co - e.y * si; tii += e.x * si + e.y * co;
        t += u; if (t >= r) t -= r;
      }
      t = (int)(((long)(r - rn2) * u) % r);
      for (int j = rp2; j < m; j++) {
        float2 e = Gd[j * c2 + k2];
        float co = tw[2 * t], si = tw[2 * t + 1];
        trr += e.x * co - e.y * si; tii += e.x * si + e.y * co;
        t += u; if (t >= r) t -= r;
      }
      TB[idx] = make_float2(trr, tii);
    }
    __syncthreads();
    for (int idx = tid; idx < nuc * c; idx += NTT) {
      int v = idx % c, i = idx / c;
      const float2* T2 = TB + i * c2;
      float base = T2[0].x;
      float cv = tw[2 * v], sv = tw[2 * v + 1];
      float co = cv, si = sv;
      float ea = 0.f, eb = 0.f;
      int k2 = 1;
      for (; k2 + 1 < c2; k2 += 2) {
        float2 e = T2[k2];
        float term = e.x * co - e.y * si;
        ea += term; eb -= term;
        ROT(co, si, cv, sv);
        e = T2[k2 + 1];
        term = e.x * co - e.y * si;
        ea += term; eb += term;
        ROT(co, si, cv, sv);
      }
      if (k2 < c2) {  // k2 = c2-1 (odd)
        float2 e = T2[k2];
        float term = e.x * co - e.y * si;
        ea += term; eb -= term;
      }
      SB[i * r + v]     = base + 2.f * ea;
      SB[i * r + v + c] = base + 2.f * eb;
    }
    __syncthreads();
    for (int idx = tid; idx < (nuc >> 1) * c; idx += NTT) {
      int jj = idx % c, i2 = idx / c;
      const float* s0 = SB + (2 * i2) * r;
      const float* s1 = SB + (2 * i2 + 1) * r;
      float pv = fmaxf(fmaxf(s0[2 * jj], s0[2 * jj + 1]), fmaxf(s1[2 * jj], s1[2 * jj + 1]));
      P[(ub / 2 + i2) * c + jj] = pv;
    }
    __syncthreads();
  }

  // ---- E: ring DFT of pooled image ----
  int hp1 = h + 1;
  for (int idx = tid; idx < c * hp1; idx += NTT) {
    int k2 = idx % hp1, i = idx / hp1;
    const float* prow = P + i * c;
    int dt = (2 * k2) % r;
    float cd = tw[2 * dt], sd = tw[2 * dt + 1];
    float co = 1.f, si = 0.f;
    float ar = 0.f, ai = 0.f;
    for (int jj = 0; jj < c; jj++) {
      float pv = prow[jj];
      ar += pv * co; ai -= pv * si;
      ROT(co, si, cd, sd);
    }
    P1[idx] = make_float2(ar, ai);
  }
  __syncthreads();
  float invcc = 1.0f / ((float)c * (float)c);
  float2* ringp = g_ring + ((size_t)ch * 57 + (size_t)((r - 16) >> 1)) * 132;
  if (r == 16) {
    for (int idx = tid; idx < 40; idx += NTT) {
      int k2 = idx % 5, k1 = idx / 5;
      int dt = (2 * k1) % r;
      float cd = tw[2 * dt], sd = tw[2 * dt + 1];
      float co = 1.f, si = 0.f;
      float ar = 0.f, ai = 0.f;
      for (int i = 0; i < c; i++) {
        float2 e = P1[i * hp1 + k2];
        ar += e.x * co + e.y * si; ai += e.y * co - e.x * si;
        ROT(co, si, cd, sd);
      }
      ringp[idx] = make_float2(ar * invcc, ai * invcc);
    }
  } else {
    int nA = hp1, total = 2 * nA + c;
    for (int idx = tid; idx < total; idx += NTT) {
      int k1, k2;
      if (idx < nA) { k1 = h; k2 = idx; }
      else if (idx < 2 * nA) { k1 = c - h; k2 = idx - nA; }
      else { k1 = idx - 2 * nA; k2 = h; }
      int dt = (2 * k1) % r;
      float cd = tw[2 * dt], sd = tw[2 * dt + 1];
      float co = 1.f, si = 0.f;
      float ar = 0.f, ai = 0.f;
      for (int i = 0; i < c; i++) {
        float2 e = P1[i * hp1 + k2];
        ar += e.x * co + e.y * si; ai += e.y * co - e.x * si;
        ROT(co, si, cd, sd);
      }
      ringp[idx] = make_float2(ar * invcc, ai * invcc);
    }
  }
}

// ---------------------------------------------------------------------------
// Final assembly: out = Hermitian-extension projection of x_out (no FFTs).
// ---------------------------------------------------------------------------
__device__ __forceinline__ float2 loadA(int ch, int k1, int k2) {
  int o = g_owner[k1 * 33 + k2];
  if (o < 0) return make_float2(0.f, 0.f);
  return g_ring[((size_t)ch * 57 + (o >> 8)) * 132 + (o & 255)];
}

__global__ __launch_bounds__(NT) void assemble_kernel(float* __restrict__ out) {
  size_t gid = (size_t)blockIdx.x * NT + threadIdx.x;
  if (gid >= (size_t)NCH * 4096) return;
  int ch = (int)(gid >> 12);
  int rem = (int)(gid & 4095);
  int k1 = rem >> 6, k2f = rem & 63;
  float2 v;
  if (k2f <= 32) {
    float2 a = loadA(ch, k1, k2f);
    if (k2f == 0 || k2f == 32) {
      float2 b = loadA(ch, (64 - k1) & 63, k2f);
      v = make_float2(0.5f * (a.x + b.x), 0.5f * (a.y - b.y));
    } else v = a;
  } else {
    float2 a = loadA(ch, (64 - k1) & 63, 64 - k2f);
    v = make_float2(a.x, -a.y);
  }
  out[2 * gid] = v.x;
  out[2 * gid + 1] = v.y;
}

// ---------------------------------------------------------------------------
static int lds_floats(int r, int ntt) {
  int nb = (ntt == 512) ? 8 : 4;
  int nu = (ntt == 512) ? 16 : 8;
  int c = r / 2, cp1 = c + 1, m = c, c2 = c / 2 + 1, h = c / 2;
  int sp = (cp1 & 1) ? cp1 : cp1 + 1;
  bool is128 = (r == 128);
  int o = 2 * r;
  if (!is128) o += 2 * r * sp;
  o += 2 * m * c2;
  if (!is128) o += 2 * nb * r;
  o += nu * r;
  o += 2 * nu * c2;
  if (is128) o += c * c + 2 * c * (h + 1);
  return o;
}

extern "C" void kernel_launch(void* const* d_in, const int* in_sizes, int n_in,
                              void* d_out, int out_size, void* d_ws, size_t ws_size,
                              hipStream_t stream) {
  (void)in_sizes; (void)n_in; (void)d_ws; (void)ws_size; (void)out_size;
  const float* x = (const float*)d_in[0];
  float* out = (float*)d_out;

  hipFuncSetAttribute(reinterpret_cast<const void*>(pipe_kernel<512>),
                      hipFuncAttributeMaxDynamicSharedMemorySize, 160 * 1024);
  hipFuncSetAttribute(reinterpret_cast<const void*>(pipe_kernel<256>),
                      hipFuncAttributeMaxDynamicSharedMemorySize, 160 * 1024);

  hipLaunchKernelGGL(owner_kernel, dim3(9), dim3(NT), 0, stream);
  hipLaunchKernelGGL(r1_kernel, dim3(NCH * 8), dim3(NT), 0, stream, x);
  hipLaunchKernelGGL(r2_kernel, dim3(NCH * 9), dim3(NT), 0, stream);

  hipLaunchKernelGGL(pipe_kernel<512>, dim3(15 * NCH), dim3(512),
                     (size_t)lds_floats(126, 512) * 4, stream, x, 126); // 98..126
  hipLaunchKernelGGL(pipe_kernel<512>, dim3(1 * NCH), dim3(512),
                     (size_t)lds_floats(128, 512) * 4, stream, x, 128); // 128
  hipLaunchKernelGGL(pipe_kernel<512>, dim3(16 * NCH), dim3(512),
                     (size_t)lds_floats(96, 512) * 4, stream, x, 96);   // 66..96
  hipLaunchKernelGGL(pipe_kernel<256>, dim3(16 * NCH), dim3(NT),
                     (size_t)lds_floats(64, 256) * 4, stream, x, 64);   // 34..64
  hipLaunchKernelGGL(pipe_kernel<256>, dim3(9 * NCH), dim3(NT),
                     (size_t)lds_floats(32, 256) * 4, stream, x, 32);   // 16..32

  hipLaunchKernelGGL(assemble_kernel, dim3((NCH * 4096) / NT), dim3(NT), 0, stream, out);
}

// Round 3
// 27043.069 us; speedup vs baseline: 3.0278x; 1.4134x over previous
//
#include <hip/hip_runtime.h>
#include <math.h>

#define NCH 2048
#define NT 256

// Static device scratch (avoids any assumption about ws_size).
__device__ float2 g_X[(size_t)NCH * 128 * 65];     // 136 MB
__device__ float2 g_Y[(size_t)NCH * 128 * 65];     // 136 MB
__device__ float2 g_ring[(size_t)NCH * 57 * 132];  // 123 MB
__device__ int    g_owner[64 * 33];

__device__ __forceinline__ float gelu_exact(float v) {
  return 0.5f * v * (1.0f + erff(v * 0.70710678118654752440f));
}

// incremental complex rotation: (co,si) *= (cs,ss)
#define ROT(co, si, cs, ss) { float _n = co * cs - si * ss; si = si * cs + co * ss; co = _n; }

// ---------------------------------------------------------------------------
// R1: row-wise DFT along v: Y[ch,u,k2] = sum_v x[ch,u,v] e^{-2pi i k2 v/128}
// ---------------------------------------------------------------------------
__global__ __launch_bounds__(NT) void r1_kernel(const float* __restrict__ x) {
  __shared__ float xb[16 * 128];
  __shared__ float tw[256];
  int ch = blockIdx.x >> 3, grp = blockIdx.x & 7;
  int tid = threadIdx.x;
  for (int t = tid; t < 128; t += NT) {
    float s, co; sincosf(6.283185307179586f * (float)t / 128.0f, &s, &co);
    tw[2 * t] = co; tw[2 * t + 1] = s;
  }
  const float* xp = x + ((size_t)ch * 128 + grp * 16) * 128;
  for (int i = tid; i < 16 * 128; i += NT) xb[i] = xp[i];
  __syncthreads();
  for (int idx = tid; idx < 16 * 65; idx += NT) {
    int u = idx / 65, k2 = idx - 65 * u;
    const float* row = xb + u * 128;
    float cb = tw[2 * k2], sbr = tw[2 * k2 + 1];
    int t2 = (2 * k2) & 127;
    float cs = tw[2 * t2], ss = tw[2 * t2 + 1];
    float ca = 1.f, sa = 0.f;
    float ar = 0.f, ai = 0.f;
    for (int v = 0; v < 128; v += 2) {
      float x0 = row[v], x1 = row[v + 1];
      ar += x0 * ca; ai -= x0 * sa;
      ar += x1 * cb; ai -= x1 * sbr;
      ROT(ca, sa, cs, ss); ROT(cb, sbr, cs, ss);
    }
    g_Y[((size_t)ch * 128 + grp * 16 + u) * 65 + k2] = make_float2(ar, ai);
  }
}

// ---------------------------------------------------------------------------
// R2: col-wise DFT along u + 1/16384 norm. Pairs k1 and k1+64 via (-1)^u.
// ---------------------------------------------------------------------------
__global__ __launch_bounds__(NT) void r2_kernel() {
  __shared__ float2 yb[128 * 8];
  __shared__ float tw[256];
  int ch = blockIdx.x / 9, cg = blockIdx.x - 9 * ch;
  int c0 = cg * 8, nc = min(8, 65 - c0);
  int tid = threadIdx.x;
  for (int t = tid; t < 128; t += NT) {
    float s, co; sincosf(6.283185307179586f * (float)t / 128.0f, &s, &co);
    tw[2 * t] = co; tw[2 * t + 1] = s;
  }
  for (int i = tid; i < 128 * nc; i += NT) {
    int u = i / nc, j = i - nc * u;
    yb[u * 8 + j] = g_Y[((size_t)ch * 128 + u) * 65 + c0 + j];
  }
  __syncthreads();
  const float inv = 1.0f / 16384.0f;
  for (int idx = tid; idx < 64 * nc; idx += NT) {
    int k1 = idx & 63, j = idx >> 6;
    float cb = tw[2 * k1], sbr = tw[2 * k1 + 1];
    int t2 = (2 * k1) & 127;
    float cs = tw[2 * t2], ss = tw[2 * t2 + 1];
    float ca = 1.f, sa = 0.f;
    float ar = 0.f, ai = 0.f, br = 0.f, bi = 0.f;
    for (int u = 0; u < 128; u += 2) {
      float2 e = yb[u * 8 + j];
      float pr = e.x * ca + e.y * sa, pi = e.y * ca - e.x * sa;
      ar += pr; ai += pi; br += pr; bi += pi;
      e = yb[(u + 1) * 8 + j];
      float pr2 = e.x * cb + e.y * sbr, pi2 = e.y * cb - e.x * sbr;
      ar += pr2; ai += pi2; br -= pr2; bi -= pi2;
      ROT(ca, sa, cs, ss); ROT(cb, sbr, cs, ss);
    }
    g_X[((size_t)ch * 128 + k1) * 65 + c0 + j]      = make_float2(ar * inv, ai * inv);
    g_X[((size_t)ch * 128 + k1 + 64) * 65 + c0 + j] = make_float2(br * inv, bi * inv);
  }
}

// ---------------------------------------------------------------------------
// Owner map (reference's sequential overwrite order).
// ---------------------------------------------------------------------------
__device__ __forceinline__ int owner_slot(int rr, int k2, int ri) {
  if (ri == 0) {
    if (k2 <= 4) {
      if (rr <= 3) return rr * 5 + k2;
      if (rr >= 60) return (rr - 56) * 5 + k2;
    }
    return -1;
  }
  int res = 16 + 2 * ri, c = res / 2, h = c / 2;
  if (c & 1) {
    if (rr == h && k2 <= h) return k2;
    if (rr == 64 - h && k2 <= h) return (h + 1) + k2;
    if (k2 == h) {
      if (rr <= h) return 2 * (h + 1) + rr;
      if (rr >= 64 - h) return 2 * (h + 1) + (rr - 64 + c);
    }
  } else {
    if (rr == 64 - h && k2 <= h) return (h + 1) + k2;
    if (k2 == h) {
      if (rr >= 64 - h) return 2 * (h + 1) + (rr - 64 + c);
      if (rr < h) return 2 * (h + 1) + rr;
    }
  }
  return -1;
}

__global__ __launch_bounds__(NT) void owner_kernel() {
  int cell = blockIdx.x * NT + threadIdx.x;
  if (cell >= 64 * 33) return;
  int rr = cell / 33, k2 = cell - 33 * (cell / 33);
  int result = -1;
  for (int ri = 56; ri >= 0 && result < 0; ri--) {
    int slot = owner_slot(rr, k2, ri);
    if (slot >= 0) result = ri * 256 + slot;
  }
  g_owner[cell] = result;
}

// ---------------------------------------------------------------------------
// Per-(channel,res) pipeline. A1 fused into A2 (T-rows computed per u-block
// straight from the g_X crop; col-0/c symmetrization == Im-zeroing after DFT).
// ---------------------------------------------------------------------------
template <int NTT>
__global__ __launch_bounds__(NTT) void pipe_kernel(const float* __restrict__ x, int res_hi) {
  const int H2 = 16;   // u-pairs per TT block (TT holds 2*H2 T-rows)
  const int NU = 8;    // rows per synthesis/analysis sub-chunk
  int rorder = blockIdx.x / NCH;
  int ch = blockIdx.x - rorder * NCH;
  int r = res_hi - 2 * rorder;
  const int tid = threadIdx.x;
  int c = r >> 1, cp1 = c + 1, m = c, c2 = (c >> 1) + 1, h = c >> 1;
  int rp2 = (m + 1) >> 1, rn2 = m >> 1;
  bool is128 = (r == 128);

  extern __shared__ float lds[];
  float* tw = lds;                               // 2r
  float* gdp = tw + 2 * r;                       // Gd (2*c*c2); reused as P1 in ring
  float2* Gd = (float2*)gdp;
  float* tbp = gdp + 2 * c * c2;                 // TB (2*NU*c2)
  float2* TB = (float2*)tbp;
  float* Xr = tbp + 2 * NU * c2;                 // X region (phase-dependent)
  float2* TT = (float2*)Xr;                      // A2: 2*H2 rows x cp1 complex
  float* SBa = is128 ? Xr : (Xr + 4 * H2 * cp1); // A2 spatial rows
  float* P = Xr;                                 // C/ring: pooled c x c
  float* SBc = Xr + c * c;                       // C spatial rows
  float2* P1 = (float2*)gdp;                     // ring: overlays Gd (same size)

  for (int t = tid; t < r; t += NTT) {
    float s, co; sincosf(6.283185307179586f * (float)t / (float)r, &s, &co);
    tw[2 * t] = co; tw[2 * t + 1] = s;
  }
  __syncthreads();

  const float2* Xc = g_X + (size_t)ch * (128 * 65);

  // ---- shared helpers ----
  auto do_analysis = [&](int ns) {
    // TB[i][k2] = sum_v SBa[i][v] e^{-2pi i k2 v / r}, v paired with v+c
    for (int idx = tid; idx < ns * c2; idx += NTT) {
      int k2 = idx % c2, i = idx / c2;
      const float* gp = SBa + i * r;
      float sk2 = (k2 & 1) ? -1.f : 1.f;
      float cb = tw[2 * k2], sbr = tw[2 * k2 + 1];
      int t2 = (2 * k2) % r;
      float cs = tw[2 * t2], ss = tw[2 * t2 + 1];
      float ca = 1.f, sa = 0.f;
      float ar = 0.f, ai = 0.f;
      int v = 0;
      for (; v + 1 < c; v += 2) {
        float f1 = fmaf(sk2, gp[v + c], gp[v]);
        ar += f1 * ca; ai -= f1 * sa;
        float f2 = fmaf(sk2, gp[v + 1 + c], gp[v + 1]);
        ar += f2 * cb; ai -= f2 * sbr;
        ROT(ca, sa, cs, ss); ROT(cb, sbr, cs, ss);
      }
      if (v < c) {
        float f1 = fmaf(sk2, gp[v + c], gp[v]);
        ar += f1 * ca; ai -= f1 * sa;
      }
      TB[idx] = make_float2(ar, ai);
    }
  };
  auto do_gaccum = [&](int ns, int ubase, bool first) {
    for (int idx = tid; idx < m * c2; idx += NTT) {
      int j = idx / c2, k2 = idx - j * c2;
      int f = (j < rp2) ? j : (r - rn2 + (j - rp2));
      float gr = 0.f, gi = 0.f;
      if (!first) { float2 gv = Gd[idx]; gr = gv.x; gi = gv.y; }
      int t = (f * ubase) % r;
      for (int i = 0; i < ns; i++) {
        float2 e = TB[i * c2 + k2];
        float co = tw[2 * t], si = tw[2 * t + 1];
        gr += e.x * co + e.y * si;
        gi += e.y * co - e.x * si;
        t += f; if (t >= r) t -= r;
      }
      Gd[idx] = make_float2(gr, gi);
    }
  };

  // ---- A: per u-block: col-DFT T-rows from crop, synthesis, GELU, analysis, G-accum ----
  if (!is128) {
    bool first = true;
    for (int ub = 0; ub < c; ub += H2) {
      int nuc = min(H2, c - ub);
      // TT rows for u = ub+i (slot i) and u+c (slot H2+i), from global crop
      for (int idx = tid; idx < nuc * cp1; idx += NTT) {
        int i = idx / cp1, j = idx - i * cp1;
        int u = ub + i;
        const float2* pa = Xc + j;                            // rows k1' in [0,c)
        const float2* pb = Xc + (size_t)(128 - c) * 65 + j;   // rows k1'+c
        float su = (u & 1) ? -1.f : 1.f;
        float sc_ = (c & 1) ? -su : su;
        float cb = tw[2 * u], sbr = tw[2 * u + 1];
        float cs = tw[4 * u], ss = tw[4 * u + 1];             // angle 2u (2u<r)
        float ca = 1.f, sa = 0.f;
        float axr = 0.f, axi = 0.f, bxr = 0.f, bxi = 0.f;
        int k1 = 0;
        for (; k1 + 1 < c; k1 += 2) {
          float2 e1 = pa[(size_t)k1 * 65];
          float2 e2 = pb[(size_t)k1 * 65];
          float f1x = fmaf(su, e2.x, e1.x), f1y = fmaf(su, e2.y, e1.y);
          float f2x = fmaf(sc_, e2.x, e1.x), f2y = fmaf(sc_, e2.y, e1.y);
          axr += f1x * ca - f1y * sa; axi += f1x * sa + f1y * ca;
          bxr += f2x * ca - f2y * sa; bxi += f2x * sa + f2y * ca;
          e1 = pa[(size_t)(k1 + 1) * 65];
          e2 = pb[(size_t)(k1 + 1) * 65];
          f1x = fmaf(su, e2.x, e1.x); f1y = fmaf(su, e2.y, e1.y);
          f2x = fmaf(sc_, e2.x, e1.x); f2y = fmaf(sc_, e2.y, e1.y);
          axr += f1x * cb - f1y * sbr; axi += f1x * sbr + f1y * cb;
          bxr -= f2x * cb - f2y * sbr; bxi -= f2x * sbr + f2y * cb;
          ROT(ca, sa, cs, ss); ROT(cb, sbr, cs, ss);
        }
        if (k1 < c) {
          float2 e1 = pa[(size_t)k1 * 65];
          float2 e2 = pb[(size_t)k1 * 65];
          float f1x = fmaf(su, e2.x, e1.x), f1y = fmaf(su, e2.y, e1.y);
          float f2x = fmaf(sc_, e2.x, e1.x), f2y = fmaf(sc_, e2.y, e1.y);
          axr += f1x * ca - f1y * sa; axi += f1x * sa + f1y * ca;
          bxr += f2x * ca - f2y * sa; bxi += f2x * sa + f2y * ca;
        }
        if (j == 0 || j == c) { axi = 0.f; bxi = 0.f; }  // symmetrization == Re()
        TT[i * cp1 + j]          = make_float2(axr, axi);
        TT[(H2 + i) * cp1 + j]   = make_float2(bxr, bxi);
      }
      __syncthreads();
      for (int g = 0; g < 2; g++) {
        for (int s0 = 0; s0 < nuc; s0 += NU) {
          int ns = min(NU, nuc - s0);
          int ubase = ub + s0 + g * c;
          // synthesis (v-dim) + GELU -> SBa
          for (int idx = tid; idx < ns * c; idx += NTT) {
            int v = idx % c, i = idx / c;
            const float2* Tr = TT + (g * H2 + s0 + i) * cp1;
            float s0v = Tr[0].x, scN = Tr[c].x;
            float cv = tw[2 * v], sv = tw[2 * v + 1];
            int t2 = (2 * v) % r;
            float cs = tw[2 * t2], ss = tw[2 * t2 + 1];
            float ca = cv, sa = sv, cb = cs, sbr = ss;
            float ea = 0.f, eb = 0.f;
            int k2 = 1;
            for (; k2 + 1 < c; k2 += 2) {
              float2 e = Tr[k2];
              float term = e.x * ca - e.y * sa;
              ea += term; eb -= term;
              e = Tr[k2 + 1];
              float term2 = e.x * cb - e.y * sbr;
              ea += term2; eb += term2;
              ROT(ca, sa, cs, ss); ROT(cb, sbr, cs, ss);
            }
            if (k2 < c) {
              float2 e = Tr[k2];
              float term = e.x * ca - e.y * sa;
              ea += term; eb -= term;
            }
            float sva = (v & 1) ? -scN : scN;
            float svb = ((v + c) & 1) ? -scN : scN;
            SBa[i * r + v]     = gelu_exact(s0v + sva + 2.f * ea);
            SBa[i * r + v + c] = gelu_exact(s0v + svb + 2.f * eb);
          }
          __syncthreads();
          do_analysis(ns);
          __syncthreads();
          do_gaccum(ns, ubase, first);
          first = false;
          __syncthreads();
        }
      }
    }
  } else {
    const float* xc = x + (size_t)ch * 128 * 128;
    for (int ub = 0; ub < r; ub += NU) {
      for (int idx = tid; idx < NU * r; idx += NTT) {
        int v = idx & 127, i = idx >> 7;
        SBa[i * r + v] = gelu_exact(xc[(ub + i) * 128 + v]);
      }
      __syncthreads();
      do_analysis(NU);
      __syncthreads();
      do_gaccum(NU, ub, ub == 0);
      __syncthreads();
    }
  }
  {
    float invr2 = 1.0f / ((float)r * (float)r);
    for (int idx = tid; idx < m * c2; idx += NTT) { Gd[idx].x *= invr2; Gd[idx].y *= invr2; }
  }
  __syncthreads();

  // ---- C: streamed smoothing synthesis + 2x2 maxpool into P ----
  for (int ub = 0; ub < r; ub += NU) {
    int ns = min(NU, r - ub);
    for (int idx = tid; idx < ns * c2; idx += NTT) {
      int k2 = idx % c2, i = idx / c2;
      int u = ub + i;
      float trr = 0.f, tii = 0.f;
      int t = 0;
      for (int j = 0; j < rp2; j++) {
        float2 e = Gd[j * c2 + k2];
        float co = tw[2 * t], si = tw[2 * t + 1];
        trr += e.x * co - e.y * si; tii += e.x * si + e.y * co;
        t += u; if (t >= r) t -= r;
      }
      t = (int)(((long)(r - rn2) * u) % r);
      for (int j = rp2; j < m; j++) {
        float2 e = Gd[j * c2 + k2];
        float co = tw[2 * t], si = tw[2 * t + 1];
        trr += e.x * co - e.y * si; tii += e.x * si + e.y * co;
        t += u; if (t >= r) t -= r;
      }
      TB[idx] = make_float2(trr, tii);
    }
    __syncthreads();
    for (int idx = tid; idx < ns * c; idx += NTT) {
      int v = idx % c, i = idx / c;
      const float2* T2 = TB + i * c2;
      float base = T2[0].x;
      float cv = tw[2 * v], sv = tw[2 * v + 1];
      int t2 = (2 * v) % r;
      float cs = tw[2 * t2], ss = tw[2 * t2 + 1];
      float ca = cv, sa = sv, cb = cs, sbr = ss;
      float ea = 0.f, eb = 0.f;
      int k2 = 1;
      for (; k2 + 1 < c2; k2 += 2) {
        float2 e = T2[k2];
        float term = e.x * ca - e.y * sa;
        ea += term; eb -= term;
        e = T2[k2 + 1];
        float term2 = e.x * cb - e.y * sbr;
        ea += term2; eb += term2;
        ROT(ca, sa, cs, ss); ROT(cb, sbr, cs, ss);
      }
      if (k2 < c2) {
        float2 e = T2[k2];
        float term = e.x * ca - e.y * sa;
        ea += term; eb -= term;
      }
      SBc[i * r + v]     = base + 2.f * ea;
      SBc[i * r + v + c] = base + 2.f * eb;
    }
    __syncthreads();
    for (int idx = tid; idx < (ns >> 1) * c; idx += NTT) {
      int jj = idx % c, i2 = idx / c;
      const float* s0p = SBc + (2 * i2) * r;
      const float* s1p = SBc + (2 * i2 + 1) * r;
      float pv = fmaxf(fmaxf(s0p[2 * jj], s0p[2 * jj + 1]), fmaxf(s1p[2 * jj], s1p[2 * jj + 1]));
      P[(ub / 2 + i2) * c + jj] = pv;
    }
    __syncthreads();
  }

  // ---- E: ring DFT of pooled image (P1 overlays Gd, which is now dead) ----
  int hp1 = h + 1;
  for (int idx = tid; idx < c * hp1; idx += NTT) {
    int k2 = idx % hp1, i = idx / hp1;
    const float* prow = P + i * c;
    int dt = (2 * k2) % r;
    float cb = tw[2 * dt], sbr = tw[2 * dt + 1];
    int dt2 = (2 * dt) % r;
    float cs = tw[2 * dt2], ss = tw[2 * dt2 + 1];
    float ca = 1.f, sa = 0.f;
    float ar = 0.f, ai = 0.f;
    int jj = 0;
    for (; jj + 1 < c; jj += 2) {
      float p0 = prow[jj], q0 = prow[jj + 1];
      ar += p0 * ca; ai -= p0 * sa;
      ar += q0 * cb; ai -= q0 * sbr;
      ROT(ca, sa, cs, ss); ROT(cb, sbr, cs, ss);
    }
    if (jj < c) { float p0 = prow[jj]; ar += p0 * ca; ai -= p0 * sa; }
    P1[idx] = make_float2(ar, ai);
  }
  __syncthreads();
  float invcc = 1.0f / ((float)c * (float)c);
  float2* ringp = g_ring + ((size_t)ch * 57 + (size_t)((r - 16) >> 1)) * 132;
  auto ring_out = [&](int k1, int k2, int slot) {
    int dt = (2 * k1) % r;
    float cb = tw[2 * dt], sbr = tw[2 * dt + 1];
    int dt2 = (2 * dt) % r;
    float cs = tw[2 * dt2], ss = tw[2 * dt2 + 1];
    float ca = 1.f, sa = 0.f;
    float ar = 0.f, ai = 0.f;
    int i = 0;
    for (; i + 1 < c; i += 2) {
      float2 e = P1[i * hp1 + k2];
      ar += e.x * ca + e.y * sa; ai += e.y * ca - e.x * sa;
      float2 e2 = P1[(i + 1) * hp1 + k2];
      ar += e2.x * cb + e2.y * sbr; ai += e2.y * cb - e2.x * sbr;
      ROT(ca, sa, cs, ss); ROT(cb, sbr, cs, ss);
    }
    if (i < c) {
      float2 e = P1[i * hp1 + k2];
      ar += e.x * ca + e.y * sa; ai += e.y * ca - e.x * sa;
    }
    ringp[slot] = make_float2(ar * invcc, ai * invcc);
  };
  if (r == 16) {
    for (int idx = tid; idx < 40; idx += NTT) ring_out(idx / 5, idx % 5, idx);
  } else {
    int nA = hp1, total = 2 * nA + c;
    for (int idx = tid; idx < total; idx += NTT) {
      int k1, k2;
      if (idx < nA) { k1 = h; k2 = idx; }
      else if (idx < 2 * nA) { k1 = c - h; k2 = idx - nA; }
      else { k1 = idx - 2 * nA; k2 = h; }
      ring_out(k1, k2, idx);
    }
  }
}

// ---------------------------------------------------------------------------
// Final assembly: out = Hermitian-extension projection of x_out (no FFTs).
// ---------------------------------------------------------------------------
__device__ __forceinline__ float2 loadA(int ch, int k1, int k2) {
  int o = g_owner[k1 * 33 + k2];
  if (o < 0) return make_float2(0.f, 0.f);
  return g_ring[((size_t)ch * 57 + (o >> 8)) * 132 + (o & 255)];
}

__global__ __launch_bounds__(NT) void assemble_kernel(float* __restrict__ out) {
  size_t gid = (size_t)blockIdx.x * NT + threadIdx.x;
  if (gid >= (size_t)NCH * 4096) return;
  int ch = (int)(gid >> 12);
  int rem = (int)(gid & 4095);
  int k1 = rem >> 6, k2f = rem & 63;
  float2 v;
  if (k2f <= 32) {
    float2 a = loadA(ch, k1, k2f);
    if (k2f == 0 || k2f == 32) {
      float2 b = loadA(ch, (64 - k1) & 63, k2f);
      v = make_float2(0.5f * (a.x + b.x), 0.5f * (a.y - b.y));
    } else v = a;
  } else {
    float2 a = loadA(ch, (64 - k1) & 63, 64 - k2f);
    v = make_float2(a.x, -a.y);
  }
  out[2 * gid] = v.x;
  out[2 * gid + 1] = v.y;
}

// ---------------------------------------------------------------------------
static int lds_floats(int r) {
  const int H2 = 16, NU = 8;
  int c = r / 2, cp1 = c + 1, c2 = c / 2 + 1;
  bool is128 = (r == 128);
  int common = 2 * r + 2 * c * c2 + 2 * NU * c2;
  int xa = (is128 ? 0 : 4 * H2 * cp1) + NU * r;
  int xc = c * c + NU * r;
  int X = xa > xc ? xa : xc;
  return common + X;
}

extern "C" void kernel_launch(void* const* d_in, const int* in_sizes, int n_in,
                              void* d_out, int out_size, void* d_ws, size_t ws_size,
                              hipStream_t stream) {
  (void)in_sizes; (void)n_in; (void)d_ws; (void)ws_size; (void)out_size;
  const float* x = (const float*)d_in[0];
  float* out = (float*)d_out;

  hipFuncSetAttribute(reinterpret_cast<const void*>(pipe_kernel<NT>),
                      hipFuncAttributeMaxDynamicSharedMemorySize, 160 * 1024);

  hipLaunchKernelGGL(owner_kernel, dim3(9), dim3(NT), 0, stream);
  hipLaunchKernelGGL(r1_kernel, dim3(NCH * 8), dim3(NT), 0, stream, x);
  hipLaunchKernelGGL(r2_kernel, dim3(NCH * 9), dim3(NT), 0, stream);

  hipLaunchKernelGGL(pipe_kernel<NT>, dim3(15 * NCH), dim3(NT),
                     (size_t)lds_floats(126) * 4, stream, x, 126); // 98..126, 39.6KB -> 4 blk/CU
  hipLaunchKernelGGL(pipe_kernel<NT>, dim3(1 * NCH), dim3(NT),
                     (size_t)lds_floats(128) * 4, stream, x, 128); // 128 (identity stage A)
  hipLaunchKernelGGL(pipe_kernel<NT>, dim3(16 * NCH), dim3(NT),
                     (size_t)lds_floats(96) * 4, stream, x, 96);   // 66..96, 27.6KB -> 5 blk/CU
  hipLaunchKernelGGL(pipe_kernel<NT>, dim3(16 * NCH), dim3(NT),
                     (size_t)lds_floats(64) * 4, stream, x, 64);   // 34..64, 16.4KB -> 8 blk/CU
  hipLaunchKernelGGL(pipe_kernel<NT>, dim3(9 * NCH), dim3(NT),
                     (size_t)lds_floats(32) * 4, stream, x, 32);   // 16..32

  hipLaunchKernelGGL(assemble_kernel, dim3((NCH * 4096) / NT), dim3(NT), 0, stream, out);
}